// Round 6
// baseline (196.369 us; speedup 1.0000x reference)
//
#include <hip/hip_runtime.h>
#include <hip/hip_bf16.h>
#include <cstdint>

typedef float f32x4 __attribute__((ext_vector_type(4)));
typedef short bf16x8 __attribute__((ext_vector_type(8)));
typedef short bf16x4 __attribute__((ext_vector_type(4)));
typedef unsigned short u16;

#define B_    4
#define S_    2048
#define H_    8
#define D_    64
#define M_    8192   // B_*S_

// workspace offsets (bytes)
#define OFF_CBF   0UL
#define OFF_XBF   8388608UL
#define OFF_QBH   16777216UL
#define OFF_VBH   25165824UL
#define OFF_VTBH  33554432UL
#define OFF_ATTN  41943040UL
#define OFF_WQT   50331648UL
#define OFF_WVT   50855936UL
#define OFF_WOT   51380224UL
#define OFF_BIAS  51904512UL
#define OFF_COS   51910656UL
#define OFF_SIN   52172800UL
#define WS_NEEDED 52434944UL

__device__ __forceinline__ u16 f2bf(float f){
    union { float f; uint32_t u; } v; v.f = f;
    uint32_t r = (v.u + 0x7fffu + ((v.u >> 16) & 1u)) >> 16;
    return (u16)r;
}
__device__ __forceinline__ float bf2f(u16 h){
    union { uint32_t u; float f; } v; v.u = ((uint32_t)h) << 16;
    return v.f;
}
__device__ __forceinline__ uint32_t fbits(float f){
    union { float f; uint32_t u; } v; v.f = f; return v.u;
}

// 16x16x16 bf16 MFMA (K=16): B-operand layout (n=lane&15, k=quad*4+e) matches
// the 16x16 C/D layout exactly -> P feeds PV straight from QK^T result regs.
__device__ __forceinline__ f32x4 mfma16(bf16x4 a, bf16x4 b, f32x4 c){
#if __has_builtin(__builtin_amdgcn_mfma_f32_16x16x16bf16_1k)
    return __builtin_amdgcn_mfma_f32_16x16x16bf16_1k(a, b, c, 0, 0, 0);
#else
    asm volatile("v_mfma_f32_16x16x16_bf16 %0, %1, %2, %0" : "+v"(c) : "v"(a), "v"(b));
    return c;
#endif
}

// 16B-chunk XOR swizzle within each 64-elem (128B) row segment.
__device__ __forceinline__ int swz(int row, int col){
    return (col & ~63) | ((((col >> 3) & 7) ^ (row & 7)) << 3) | (col & 7);
}

// inline dtype probe: wave ballot over x's first 128 u16 halves.
__device__ __forceinline__ int detect_f32(const void* x_in){
    int lane = threadIdx.x & 63;
    ushort2 dv = ((const ushort2*)x_in)[lane];
    bool hit = ((((dv.x >> 7) & 0xFF) >= 160) || (((dv.y >> 7) & 0xFF) >= 160));
    return __ballot(hit) != 0ULL;
}

// async global->LDS 16B/lane; global addr per-lane, LDS base wave-uniform (+lane*16)
__device__ __forceinline__ void gload_lds16(const u16* g, u16* l){
    __builtin_amdgcn_global_load_lds(
        (const __attribute__((address_space(1))) void*)g,
        (__attribute__((address_space(3))) void*)l, 16, 0, 0);
}

// ---- merged prep: activation convert (swizzled), weight T+convert (swizzled),
//      biases, rope tables ----
__global__ void k_prep(const void* c_in, const void* x_in,
                       const void* Wq, const void* Wv, const void* Wo,
                       const void* bq, const void* bv, const void* bo,
                       u16* c_bf, u16* x_bf,
                       u16* Wqt, u16* Wvt, u16* Wot, float* bias_ws,
                       float* cos_t, float* sin_t){
    int bid = blockIdx.x;
    if (bid >= 11264){                       // rope tables
        int idx = (bid - 11264) * 256 + threadIdx.x;   // 0..65535
        int pos = idx >> 5, j = idx & 31;
        double theta = pow(10000.0, -(double)j / 32.0);
        double rev = ((double)pos * theta) * 0.15915494309189535;
        rev -= floor(rev);
        float fr = (float)rev;
        cos_t[idx] = __builtin_amdgcn_cosf(fr);
        sin_t[idx] = __builtin_amdgcn_sinf(fr);
        return;
    }
    if (bid >= 8192){                        // weights + biases
        int f = detect_f32(x_in);
        int wi = (bid - 8192) >> 10;
        int idx = ((bid - 8192) & 1023) * 256 + threadIdx.x;   // 0..262143
        int k = idx >> 9, n = idx & 511;
        const void* W; u16* Wt; const void* bb;
        if (wi == 0){ W = Wq; Wt = Wqt; bb = bq; }
        else if (wi == 1){ W = Wv; Wt = Wvt; bb = bv; }
        else { W = Wo; Wt = Wot; bb = bo; }
        float v = f ? ((const float*)W)[idx] : bf2f(((const u16*)W)[idx]);
        Wt[n * 512 + swz(n, k)] = f2bf(v);
        if (idx < 512){
            float b = f ? ((const float*)bb)[idx] : bf2f(((const u16*)bb)[idx]);
            bias_ws[wi * 512 + idx] = b;
        }
        return;
    }
    int f = detect_f32(x_in);
    int isx = bid >= 4096;
    int t = (bid & 4095) * 256 + threadIdx.x;
    const void* src = isx ? x_in : c_in;
    u16* dst = isx ? x_bf : c_bf;
    int e0 = t * 4, row = e0 >> 9, col = e0 & 511;
    size_t didx = (size_t)row * 512 + swz(row, col);
    ushort4 o;
    if (f){
        float4 v = ((const float4*)src)[t];
        o.x = f2bf(v.x); o.y = f2bf(v.y); o.z = f2bf(v.z); o.w = f2bf(v.w);
    } else {
        o = ((const ushort4*)src)[t];
    }
    *(ushort4*)(dst + didx) = o;
}

// ---- Q/V projection GEMM: 128x128 tile, BK=64, double-buffered LDS ----
// z=0: Q roped+prescaled -> Qbh[b,h,s,d] (plain layout)
// z=1: V -> Vbh[b,h,s,d] and Vtbh[b,h,d,s], both chunk-SWIZZLED for k_attn
__global__ __launch_bounds__(256) void k_gemm_qv(
    const u16* __restrict__ c_bf, const u16* __restrict__ x_bf,
    const u16* __restrict__ Wqt, const u16* __restrict__ Wvt,
    const float* __restrict__ bias_ws,
    const float* __restrict__ cos_t, const float* __restrict__ sin_t,
    u16* __restrict__ Qbh, u16* __restrict__ Vbh, u16* __restrict__ Vtbh)
{
    __shared__ __align__(16) u16 Als[2][128 * 64];
    __shared__ __align__(16) u16 Bls[2][128 * 64];
    const int w = threadIdx.x >> 6, lane = threadIdx.x & 63;
    const int g = lane >> 4, cq = lane & 15;
    const int wm = w & 1, wn = w >> 1;
    const int z = blockIdx.z;
    const u16* A  = z ? x_bf : c_bf;
    const u16* Wt = z ? Wvt : Wqt;
    const float* bias = bias_ws + (z ? 512 : 0);
    const int m0b = blockIdx.x * 128, n0b = blockIdx.y * 128;
    const int m0 = m0b + wm * 64, n0 = n0b + wn * 64;
    const int swzi = ((cq & 7) << 3);

    int srow[4], scol[4];
    #pragma unroll
    for (int i = 0; i < 4; i++){
        int flat = (w * 4 + i) * 64 + lane;
        srow[i] = flat >> 3; scol[i] = (flat & 7) * 8;
    }

    const f32x4 zero = {0.f, 0.f, 0.f, 0.f};
    f32x4 acc[4][4];
    #pragma unroll
    for (int i = 0; i < 4; i++)
        #pragma unroll
        for (int j = 0; j < 4; j++) acc[i][j] = zero;

    #pragma unroll
    for (int i = 0; i < 4; i++){
        gload_lds16(A  + (size_t)(m0b + srow[i]) * 512 + scol[i], &Als[0][(w*4 + i) * 512]);
        gload_lds16(Wt + (size_t)(n0b + srow[i]) * 512 + scol[i], &Bls[0][(w*4 + i) * 512]);
    }

    for (int kt = 0; kt < 8; kt++){
        const int buf = kt & 1;
        __builtin_amdgcn_s_waitcnt(0x0F70);   // vmcnt(0)
        __syncthreads();
        if (kt < 7){
            const int kk = (kt + 1) * 64;
            #pragma unroll
            for (int i = 0; i < 4; i++){
                gload_lds16(A  + (size_t)(m0b + srow[i]) * 512 + kk + scol[i], &Als[buf^1][(w*4 + i) * 512]);
                gload_lds16(Wt + (size_t)(n0b + srow[i]) * 512 + kk + scol[i], &Bls[buf^1][(w*4 + i) * 512]);
            }
        }
        #pragma unroll
        for (int ks = 0; ks < 2; ks++){
            const int cs = ((ks * 4 + g) << 3) ^ swzi;
            bf16x8 a[4], b[4];
            #pragma unroll
            for (int mt = 0; mt < 4; mt++)
                a[mt] = *(const bf16x8*)&Als[buf][(wm*64 + mt*16 + cq) * 64 + cs];
            #pragma unroll
            for (int nt = 0; nt < 4; nt++)
                b[nt] = *(const bf16x8*)&Bls[buf][(wn*64 + nt*16 + cq) * 64 + cs];
            #pragma unroll
            for (int mt = 0; mt < 4; mt++)
                #pragma unroll
                for (int nt = 0; nt < 4; nt++)
                    acc[mt][nt] = __builtin_amdgcn_mfma_f32_16x16x32_bf16(a[mt], b[nt], acc[mt][nt], 0, 0, 0);
        }
    }
    __syncthreads();

    #pragma unroll
    for (int nt = 0; nt < 4; nt++){
        float bvv = bias[n0 + nt*16 + cq];
        #pragma unroll
        for (int mt = 0; mt < 4; mt++) acc[mt][nt] += bvv;
    }
    const int h = n0 >> 6;
    if (z == 0){
        const float SCL = 0.125f * 1.4426950408889634f;
        #pragma unroll
        for (int mt = 0; mt < 4; mt++){
            #pragma unroll
            for (int r = 0; r < 4; r++){
                int row = m0 + mt*16 + g*4 + r;
                int b_idx = row >> 11, si = row & 2047;
                size_t base = ((size_t)(b_idx*8 + h) * 2048 + si) * 64;
                #pragma unroll
                for (int nt = 0; nt < 2; nt++){
                    int dj = nt*16 + cq;
                    float cv = cos_t[si*32 + dj], sv = sin_t[si*32 + dj];
                    float x1 = acc[mt][nt][r], x2 = acc[mt][nt+2][r];
                    Qbh[base + dj]      = f2bf((x1*cv - x2*sv) * SCL);
                    Qbh[base + dj + 32] = f2bf((x2*cv + x1*sv) * SCL);
                }
            }
        }
    } else {
        float* ltw = ((float*)&Als[0][0]) + w * (16 * 65);
        const int b_idx = m0 >> 11, si0 = m0 & 2047;
        const size_t tbase = ((size_t)(b_idx*8 + h) * 64) * 2048;
        // Vbh: swizzle chunks within each 64-d row (row key = s index)
        #pragma unroll
        for (int mt = 0; mt < 4; mt++)
            #pragma unroll
            for (int r = 0; r < 4; r++){
                int row = m0 + mt*16 + g*4 + r;
                int bi = row >> 11, si = row & 2047;
                size_t base = ((size_t)(bi*8 + h) * 2048 + si) * 64;
                int s7 = si & 7;
                #pragma unroll
                for (int nt = 0; nt < 4; nt++){
                    int dj = nt*16 + cq;
                    int col = ((((dj >> 3) ^ s7) & 7) << 3) | (dj & 7);
                    Vbh[base + col] = f2bf(acc[mt][nt][r]);
                }
            }
        // Vtbh: swizzle chunks within each 64-s segment (row key = d index)
        #pragma unroll
        for (int nt = 0; nt < 4; nt++){
            #pragma unroll
            for (int mt = 0; mt < 4; mt++)
                #pragma unroll
                for (int r = 0; r < 4; r++)
                    ltw[cq * 65 + mt*16 + g*4 + r] = acc[mt][nt][r];
            __builtin_amdgcn_wave_barrier();
            #pragma unroll
            for (int dd = 0; dd < 16; dd++){
                float v = ltw[dd * 65 + lane];
                int col = ((((lane >> 3) ^ (dd & 7)) & 7) << 3) | (lane & 7);
                Vtbh[tbase + (size_t)(nt*16 + dd) * 2048 + si0 + col] = f2bf(v);
            }
            __builtin_amdgcn_wave_barrier();
        }
    }
}

// ---- flash attention v5: S^T trick, P stays in registers, async staging ----
// S^T = mfma(A=V-frag, B=Q-frag); its C-layout == 16x16x16 B-operand layout,
// so PV (O^T = Vt^T-as-A x P^T-as-B) needs NO LDS for P. One barrier/tile.
__global__ __launch_bounds__(256) void k_attn(
    const u16* __restrict__ Qbh, const u16* __restrict__ Vbh,
    const u16* __restrict__ Vtbh, u16* __restrict__ attn)
{
    __shared__ __align__(16) u16 Vs[2][64 * 64];    // swizzled V tile
    __shared__ __align__(16) u16 Vts[2][64 * 64];   // swizzled Vt tile
    const int w = threadIdx.x >> 6, lane = threadIdx.x & 63;
    const int g = lane >> 4, cq = lane & 15;
    const int s7 = cq & 7;
    const int bh = blockIdx.y;
    const int i0 = blockIdx.x * 128 + w * 32;

    bf16x8 aq[2][2];
    #pragma unroll
    for (int mt = 0; mt < 2; mt++)
        #pragma unroll
        for (int kk = 0; kk < 2; kk++)
            aq[mt][kk] = *(const bf16x8*)(Qbh + ((size_t)bh*2048 + i0 + mt*16 + cq)*64 + kk*32 + g*8);

    // staging: wave w covers LDS u16 ranges [(w*2+i)*512, +512), i=0,1
    const int c0 = (w * 2) * 512, c1 = c0 + 512;
    const u16* gvs0 = Vbh + (size_t)bh * 131072 + c0 + lane * 8;   // linear copy
    const u16* gvs1 = gvs0 + 512;
    const int dr0 = (w * 2) * 8 + (lane >> 3);
    const u16* gvt0 = Vtbh + ((size_t)bh * 64 + dr0) * 2048 + (lane & 7) * 8;
    const u16* gvt1 = gvt0 + 8 * 2048;

    gload_lds16(gvs0, &Vs[0][c0]);
    gload_lds16(gvs1, &Vs[0][c1]);
    gload_lds16(gvt0, &Vts[0][c0]);
    gload_lds16(gvt1, &Vts[0][c1]);

    const f32x4 zero = {0.f, 0.f, 0.f, 0.f};
    f32x4 o[2][4]; float fl[2] = {0.f, 0.f};
    #pragma unroll
    for (int mt = 0; mt < 2; mt++)
        #pragma unroll
        for (int t = 0; t < 4; t++) o[mt][t] = zero;

    for (int jt = 0; jt < 32; jt++){
        const int buf = jt & 1;
        __builtin_amdgcn_s_waitcnt(0x0F70);   // vmcnt(0): my stage landed
        __syncthreads();                       // everyone's landed / prev reads done
        if (jt < 31){
            const size_t os = (size_t)(jt + 1) * 4096, ot = (size_t)(jt + 1) * 64;
            gload_lds16(gvs0 + os, &Vs[buf^1][c0]);
            gload_lds16(gvs1 + os, &Vs[buf^1][c1]);
            gload_lds16(gvt0 + ot, &Vts[buf^1][c0]);
            gload_lds16(gvt1 + ot, &Vts[buf^1][c1]);
        }
        // QK^T (transposed scores) + exp2 + pack to PV B-operands, all in regs
        bf16x4 pk[2][4];
        #pragma unroll
        for (int t = 0; t < 4; t++){
            bf16x8 bv0 = *(const bf16x8*)&Vs[buf][(t*16 + cq)*64 + ((g ^ s7) << 3)];
            bf16x8 bv1 = *(const bf16x8*)&Vs[buf][(t*16 + cq)*64 + (((4 + g) ^ s7) << 3)];
            #pragma unroll
            for (int mt = 0; mt < 2; mt++){
                f32x4 s = __builtin_amdgcn_mfma_f32_16x16x32_bf16(bv0, aq[mt][0], zero, 0, 0, 0);
                s = __builtin_amdgcn_mfma_f32_16x16x32_bf16(bv1, aq[mt][1], s, 0, 0, 0);
                #pragma unroll
                for (int r = 0; r < 4; r++) s[r] = __builtin_amdgcn_exp2f(s[r]);
                fl[mt] += (s[0] + s[1]) + (s[2] + s[3]);
                union { bf16x4 v; uint32_t wd[2]; } u;
                u.wd[0] = (fbits(s[0]) >> 16) | (fbits(s[1]) & 0xffff0000u);
                u.wd[1] = (fbits(s[2]) >> 16) | (fbits(s[3]) & 0xffff0000u);
                pk[mt][t] = u.v;
            }
        }
        // PV: O^T += Vt-frag x P^T-frag (16x16x16), P from registers
        #pragma unroll
        for (int t = 0; t < 4; t++){
            const int chk = ((t*2 + (g >> 1)) ^ s7) & 7;
            #pragma unroll
            for (int tn = 0; tn < 4; tn++){
                bf16x4 bt = *(const bf16x4*)&Vts[buf][(tn*16 + cq)*64 + (chk << 3) + (g & 1)*4];
                o[0][tn] = mfma16(bt, pk[0][t], o[0][tn]);
                o[1][tn] = mfma16(bt, pk[1][t], o[1][tn]);
            }
        }
    }
    // row-sum: i is fixed per lane; reduce across the 4 quads
    const int b_idx = bh >> 3, h = bh & 7;
    #pragma unroll
    for (int mt = 0; mt < 2; mt++){
        float sum = fl[mt];
        sum += __shfl_xor(sum, 16);
        sum += __shfl_xor(sum, 32);
        float inv = 1.f / sum;
        int row = b_idx*2048 + i0 + mt*16 + cq;
        #pragma unroll
        for (int tn = 0; tn < 4; tn++){
            f32x4 ov = o[mt][tn] * inv;
            uint2 pw;
            pw.x = (fbits(ov[0]) >> 16) | (fbits(ov[1]) & 0xffff0000u);
            pw.y = (fbits(ov[2]) >> 16) | (fbits(ov[3]) & 0xffff0000u);
            int chunk = ((tn*2 + (g >> 1)) ^ s7) & 7;
            int col = h*64 + (chunk << 3) + (g & 1)*4;
            *(uint2*)&attn[(size_t)row * 512 + col] = pw;   // pre-swizzled for gemm_out
        }
    }
}

// ---- output GEMM: 128x64 tile, BK=64, double-buffered, + bias + residual ----
__global__ __launch_bounds__(256) void k_gemm_out(
    const u16* __restrict__ attn, const u16* __restrict__ Wot,
    const float* __restrict__ bias_ws, const void* __restrict__ x_in,
    void* __restrict__ out)
{
    __shared__ __align__(16) u16 Als[2][128 * 64];
    __shared__ __align__(16) u16 Bls[2][64 * 64];
    const int w = threadIdx.x >> 6, lane = threadIdx.x & 63;
    const int g = lane >> 4, cq = lane & 15;
    const int wm = w & 1, wn = w >> 1;
    const int m0b = blockIdx.x * 128, n0b = blockIdx.y * 64;
    const int m0 = m0b + wm * 64, n0 = n0b + wn * 32;
    const int f = detect_f32(x_in);
    const int swzi = ((cq & 7) << 3);

    int sra[4], sca[4], srb[2], scb[2];
    #pragma unroll
    for (int i = 0; i < 4; i++){
        int flat = (w * 4 + i) * 64 + lane;
        sra[i] = flat >> 3; sca[i] = (flat & 7) * 8;
    }
    #pragma unroll
    for (int i = 0; i < 2; i++){
        int flat = (w * 2 + i) * 64 + lane;
        srb[i] = flat >> 3; scb[i] = (flat & 7) * 8;
    }

    const f32x4 zero = {0.f, 0.f, 0.f, 0.f};
    f32x4 acc[4][2];
    #pragma unroll
    for (int i = 0; i < 4; i++)
        #pragma unroll
        for (int j = 0; j < 2; j++) acc[i][j] = zero;

    #pragma unroll
    for (int i = 0; i < 4; i++)
        gload_lds16(attn + (size_t)(m0b + sra[i]) * 512 + sca[i], &Als[0][(w*4 + i) * 512]);
    #pragma unroll
    for (int i = 0; i < 2; i++)
        gload_lds16(Wot + (size_t)(n0b + srb[i]) * 512 + scb[i], &Bls[0][(w*2 + i) * 512]);

    for (int kt = 0; kt < 8; kt++){
        const int buf = kt & 1;
        __builtin_amdgcn_s_waitcnt(0x0F70);
        __syncthreads();
        if (kt < 7){
            const int kk = (kt + 1) * 64;
            #pragma unroll
            for (int i = 0; i < 4; i++)
                gload_lds16(attn + (size_t)(m0b + sra[i]) * 512 + kk + sca[i], &Als[buf^1][(w*4 + i) * 512]);
            #pragma unroll
            for (int i = 0; i < 2; i++)
                gload_lds16(Wot + (size_t)(n0b + srb[i]) * 512 + kk + scb[i], &Bls[buf^1][(w*2 + i) * 512]);
        }
        #pragma unroll
        for (int ks = 0; ks < 2; ks++){
            const int cs = ((ks * 4 + g) << 3) ^ swzi;
            bf16x8 a[4], b[2];
            #pragma unroll
            for (int mt = 0; mt < 4; mt++)
                a[mt] = *(const bf16x8*)&Als[buf][(wm*64 + mt*16 + cq) * 64 + cs];
            #pragma unroll
            for (int nt = 0; nt < 2; nt++)
                b[nt] = *(const bf16x8*)&Bls[buf][(wn*32 + nt*16 + cq) * 64 + cs];
            #pragma unroll
            for (int mt = 0; mt < 4; mt++)
                #pragma unroll
                for (int nt = 0; nt < 2; nt++)
                    acc[mt][nt] = __builtin_amdgcn_mfma_f32_16x16x32_bf16(a[mt], b[nt], acc[mt][nt], 0, 0, 0);
        }
    }
    #pragma unroll
    for (int mt = 0; mt < 4; mt++)
        #pragma unroll
        for (int nt = 0; nt < 2; nt++)
            #pragma unroll
            for (int r = 0; r < 4; r++){
                int row = m0 + mt*16 + g*4 + r;
                int col = n0 + nt*16 + cq;
                size_t idx = (size_t)row * 512 + col;
                float resid = f ? ((const float*)x_in)[idx] : bf2f(((const u16*)x_in)[idx]);
                float v = acc[mt][nt][r] + bias_ws[1024 + col] + resid;
                if (f) ((float*)out)[idx] = v;
                else   ((u16*)out)[idx] = f2bf(v);
            }
}

extern "C" void kernel_launch(void* const* d_in, const int* in_sizes, int n_in,
                              void* d_out, int out_size, void* d_ws, size_t ws_size,
                              hipStream_t stream){
    const void* x_in = d_in[0];
    const void* c_in = d_in[1];
    const void* Wq = d_in[2]; const void* bq = d_in[3];
    const void* Wv = d_in[6]; const void* bv = d_in[7];
    const void* Wo = d_in[8]; const void* bo = d_in[9];

    if (ws_size < WS_NEEDED){
        hipMemsetAsync(d_out, 0, (size_t)out_size * 2, stream);
        return;
    }
    char* ws = (char*)d_ws;
    u16* c_bf  = (u16*)(ws + OFF_CBF);
    u16* x_bf  = (u16*)(ws + OFF_XBF);
    u16* Qbh   = (u16*)(ws + OFF_QBH);
    u16* Vbh   = (u16*)(ws + OFF_VBH);
    u16* Vtbh  = (u16*)(ws + OFF_VTBH);
    u16* attn  = (u16*)(ws + OFF_ATTN);
    u16* Wqt   = (u16*)(ws + OFF_WQT);
    u16* Wvt   = (u16*)(ws + OFF_WVT);
    u16* Wot   = (u16*)(ws + OFF_WOT);
    float* bias_ws = (float*)(ws + OFF_BIAS);
    float* cos_t   = (float*)(ws + OFF_COS);
    float* sin_t   = (float*)(ws + OFF_SIN);

    k_prep<<<11520, 256, 0, stream>>>(c_in, x_in, Wq, Wv, Wo, bq, bv, bo,
                                      c_bf, x_bf, Wqt, Wvt, Wot, bias_ws, cos_t, sin_t);
    k_gemm_qv<<<dim3(64, 4, 2), 256, 0, stream>>>(c_bf, x_bf, Wqt, Wvt, bias_ws,
                                                  cos_t, sin_t, Qbh, Vbh, Vtbh);
    k_attn<<<dim3(16, 32), 256, 0, stream>>>(Qbh, Vbh, Vtbh, attn);
    k_gemm_out<<<dim3(64, 8), 256, 0, stream>>>(attn, Wot, bias_ws, x_in, d_out);
}

// Round 7
// 191.730 us; speedup vs baseline: 1.0242x; 1.0242x over previous
//
#include <hip/hip_runtime.h>
#include <hip/hip_bf16.h>
#include <cstdint>

typedef float f32x4 __attribute__((ext_vector_type(4)));
typedef short bf16x8 __attribute__((ext_vector_type(8)));
typedef short bf16x4 __attribute__((ext_vector_type(4)));
typedef unsigned short u16;

#define B_    4
#define S_    2048
#define H_    8
#define D_    64
#define M_    8192   // B_*S_

// workspace offsets (bytes)
#define OFF_CBF   0UL          // c_bf during gemm_qv; partial-1 O after attn
#define OFF_XBF   8388608UL    // x_bf during gemm_qv; lsum after attn
#define OFF_QBH   16777216UL
#define OFF_VBH   25165824UL
#define OFF_VTBH  33554432UL
#define OFF_ATTN  41943040UL   // partial-0 O
#define OFF_WQT   50331648UL
#define OFF_WVT   50855936UL
#define OFF_WOT   51380224UL
#define OFF_BIAS  51904512UL
#define OFF_COS   51910656UL
#define OFF_SIN   52172800UL
#define WS_NEEDED 52434944UL

__device__ __forceinline__ u16 f2bf(float f){
    union { float f; uint32_t u; } v; v.f = f;
    uint32_t r = (v.u + 0x7fffu + ((v.u >> 16) & 1u)) >> 16;
    return (u16)r;
}
__device__ __forceinline__ float bf2f(u16 h){
    union { uint32_t u; float f; } v; v.u = ((uint32_t)h) << 16;
    return v.f;
}
__device__ __forceinline__ uint32_t fbits(float f){
    union { float f; uint32_t u; } v; v.f = f; return v.u;
}

// 16x16x16 bf16 MFMA: B-operand layout == 16x16 C/D layout, so P^T feeds PV
// straight from the QK^T result registers.
__device__ __forceinline__ f32x4 mfma16(bf16x4 a, bf16x4 b, f32x4 c){
#if __has_builtin(__builtin_amdgcn_mfma_f32_16x16x16bf16_1k)
    return __builtin_amdgcn_mfma_f32_16x16x16bf16_1k(a, b, c, 0, 0, 0);
#else
    asm volatile("v_mfma_f32_16x16x16_bf16 %0, %1, %2, %0" : "+v"(c) : "v"(a), "v"(b));
    return c;
#endif
}

// 16B-chunk XOR swizzle (used only for gemm_qv's gload_lds inputs)
__device__ __forceinline__ int swz(int row, int col){
    return (col & ~63) | ((((col >> 3) & 7) ^ (row & 7)) << 3) | (col & 7);
}

// inline dtype probe: wave ballot over x's first 128 u16 halves.
__device__ __forceinline__ int detect_f32(const void* x_in){
    int lane = threadIdx.x & 63;
    ushort2 dv = ((const ushort2*)x_in)[lane];
    bool hit = ((((dv.x >> 7) & 0xFF) >= 160) || (((dv.y >> 7) & 0xFF) >= 160));
    return __ballot(hit) != 0ULL;
}

// async global->LDS 16B/lane
__device__ __forceinline__ void gload_lds16(const u16* g, u16* l){
    __builtin_amdgcn_global_load_lds(
        (const __attribute__((address_space(1))) void*)g,
        (__attribute__((address_space(3))) void*)l, 16, 0, 0);
}

// ---- merged prep ----
__global__ void k_prep(const void* c_in, const void* x_in,
                       const void* Wq, const void* Wv, const void* Wo,
                       const void* bq, const void* bv, const void* bo,
                       u16* c_bf, u16* x_bf,
                       u16* Wqt, u16* Wvt, u16* Wot, float* bias_ws,
                       float* cos_t, float* sin_t){
    int bid = blockIdx.x;
    if (bid >= 11264){                       // rope tables
        int idx = (bid - 11264) * 256 + threadIdx.x;
        int pos = idx >> 5, j = idx & 31;
        double theta = pow(10000.0, -(double)j / 32.0);
        double rev = ((double)pos * theta) * 0.15915494309189535;
        rev -= floor(rev);
        float fr = (float)rev;
        cos_t[idx] = __builtin_amdgcn_cosf(fr);
        sin_t[idx] = __builtin_amdgcn_sinf(fr);
        return;
    }
    if (bid >= 8192){                        // weights + biases
        int f = detect_f32(x_in);
        int wi = (bid - 8192) >> 10;
        int idx = ((bid - 8192) & 1023) * 256 + threadIdx.x;
        int k = idx >> 9, n = idx & 511;
        const void* W; u16* Wt; const void* bb;
        if (wi == 0){ W = Wq; Wt = Wqt; bb = bq; }
        else if (wi == 1){ W = Wv; Wt = Wvt; bb = bv; }
        else { W = Wo; Wt = Wot; bb = bo; }
        float v = f ? ((const float*)W)[idx] : bf2f(((const u16*)W)[idx]);
        // Wq/Wv: swizzled (gload_lds path in gemm_qv); Wo: plain (VGPR-staged)
        Wt[n * 512 + (wi == 2 ? k : swz(n, k))] = f2bf(v);
        if (idx < 512){
            float b = f ? ((const float*)bb)[idx] : bf2f(((const u16*)bb)[idx]);
            bias_ws[wi * 512 + idx] = b;
        }
        return;
    }
    int f = detect_f32(x_in);
    int isx = bid >= 4096;
    int t = (bid & 4095) * 256 + threadIdx.x;
    const void* src = isx ? x_in : c_in;
    u16* dst = isx ? x_bf : c_bf;
    int e0 = t * 4, row = e0 >> 9, col = e0 & 511;
    size_t didx = (size_t)row * 512 + swz(row, col);
    ushort4 o;
    if (f){
        float4 v = ((const float4*)src)[t];
        o.x = f2bf(v.x); o.y = f2bf(v.y); o.z = f2bf(v.z); o.w = f2bf(v.w);
    } else {
        o = ((const ushort4*)src)[t];
    }
    *(ushort4*)(dst + didx) = o;
}

// ---- Q/V projection GEMM (unchanged core): 128x128, BK=64, dbuf gload_lds ----
__global__ __launch_bounds__(256) void k_gemm_qv(
    const u16* __restrict__ c_bf, const u16* __restrict__ x_bf,
    const u16* __restrict__ Wqt, const u16* __restrict__ Wvt,
    const float* __restrict__ bias_ws,
    const float* __restrict__ cos_t, const float* __restrict__ sin_t,
    u16* __restrict__ Qbh, u16* __restrict__ Vbh, u16* __restrict__ Vtbh)
{
    __shared__ __align__(16) u16 Als[2][128 * 64];
    __shared__ __align__(16) u16 Bls[2][128 * 64];
    const int w = threadIdx.x >> 6, lane = threadIdx.x & 63;
    const int g = lane >> 4, cq = lane & 15;
    const int wm = w & 1, wn = w >> 1;
    const int z = blockIdx.z;
    const u16* A  = z ? x_bf : c_bf;
    const u16* Wt = z ? Wvt : Wqt;
    const float* bias = bias_ws + (z ? 512 : 0);
    const int m0b = blockIdx.x * 128, n0b = blockIdx.y * 128;
    const int m0 = m0b + wm * 64, n0 = n0b + wn * 64;
    const int swzi = ((cq & 7) << 3);

    int srow[4], scol[4];
    #pragma unroll
    for (int i = 0; i < 4; i++){
        int flat = (w * 4 + i) * 64 + lane;
        srow[i] = flat >> 3; scol[i] = (flat & 7) * 8;
    }

    const f32x4 zero = {0.f, 0.f, 0.f, 0.f};
    f32x4 acc[4][4];
    #pragma unroll
    for (int i = 0; i < 4; i++)
        #pragma unroll
        for (int j = 0; j < 4; j++) acc[i][j] = zero;

    #pragma unroll
    for (int i = 0; i < 4; i++){
        gload_lds16(A  + (size_t)(m0b + srow[i]) * 512 + scol[i], &Als[0][(w*4 + i) * 512]);
        gload_lds16(Wt + (size_t)(n0b + srow[i]) * 512 + scol[i], &Bls[0][(w*4 + i) * 512]);
    }

    for (int kt = 0; kt < 8; kt++){
        const int buf = kt & 1;
        __builtin_amdgcn_s_waitcnt(0x0F70);   // vmcnt(0)
        __syncthreads();
        if (kt < 7){
            const int kk = (kt + 1) * 64;
            #pragma unroll
            for (int i = 0; i < 4; i++){
                gload_lds16(A  + (size_t)(m0b + srow[i]) * 512 + kk + scol[i], &Als[buf^1][(w*4 + i) * 512]);
                gload_lds16(Wt + (size_t)(n0b + srow[i]) * 512 + kk + scol[i], &Bls[buf^1][(w*4 + i) * 512]);
            }
        }
        #pragma unroll
        for (int ks = 0; ks < 2; ks++){
            const int cs = ((ks * 4 + g) << 3) ^ swzi;
            bf16x8 a[4], b[4];
            #pragma unroll
            for (int mt = 0; mt < 4; mt++)
                a[mt] = *(const bf16x8*)&Als[buf][(wm*64 + mt*16 + cq) * 64 + cs];
            #pragma unroll
            for (int nt = 0; nt < 4; nt++)
                b[nt] = *(const bf16x8*)&Bls[buf][(wn*64 + nt*16 + cq) * 64 + cs];
            #pragma unroll
            for (int mt = 0; mt < 4; mt++)
                #pragma unroll
                for (int nt = 0; nt < 4; nt++)
                    acc[mt][nt] = __builtin_amdgcn_mfma_f32_16x16x32_bf16(a[mt], b[nt], acc[mt][nt], 0, 0, 0);
        }
    }
    __syncthreads();

    #pragma unroll
    for (int nt = 0; nt < 4; nt++){
        float bvv = bias[n0 + nt*16 + cq];
        #pragma unroll
        for (int mt = 0; mt < 4; mt++) acc[mt][nt] += bvv;
    }
    const int h = n0 >> 6;
    if (z == 0){
        const float SCL = 0.125f * 1.4426950408889634f;
        #pragma unroll
        for (int mt = 0; mt < 4; mt++){
            #pragma unroll
            for (int r = 0; r < 4; r++){
                int row = m0 + mt*16 + g*4 + r;
                int b_idx = row >> 11, si = row & 2047;
                size_t base = ((size_t)(b_idx*8 + h) * 2048 + si) * 64;
                #pragma unroll
                for (int nt = 0; nt < 2; nt++){
                    int dj = nt*16 + cq;
                    float cv = cos_t[si*32 + dj], sv = sin_t[si*32 + dj];
                    float x1 = acc[mt][nt][r], x2 = acc[mt][nt+2][r];
                    Qbh[base + dj]      = f2bf((x1*cv - x2*sv) * SCL);
                    Qbh[base + dj + 32] = f2bf((x2*cv + x1*sv) * SCL);
                }
            }
        }
    } else {
        // PLAIN Vbh / Vtbh layouts (k_attn uses padded LDS now, no global swizzle)
        float* ltw = ((float*)&Als[0][0]) + w * (16 * 65);
        const int b_idx = m0 >> 11, si0 = m0 & 2047;
        const size_t tbase = ((size_t)(b_idx*8 + h) * 64) * 2048;
        #pragma unroll
        for (int mt = 0; mt < 4; mt++)
            #pragma unroll
            for (int r = 0; r < 4; r++){
                int row = m0 + mt*16 + g*4 + r;
                int bi = row >> 11, si = row & 2047;
                size_t base = ((size_t)(bi*8 + h) * 2048 + si) * 64;
                #pragma unroll
                for (int nt = 0; nt < 4; nt++)
                    Vbh[base + nt*16 + cq] = f2bf(acc[mt][nt][r]);
            }
        #pragma unroll
        for (int nt = 0; nt < 4; nt++){
            #pragma unroll
            for (int mt = 0; mt < 4; mt++)
                #pragma unroll
                for (int r = 0; r < 4; r++)
                    ltw[cq * 65 + mt*16 + g*4 + r] = acc[mt][nt][r];
            __builtin_amdgcn_wave_barrier();
            #pragma unroll
            for (int dd = 0; dd < 16; dd++){
                float v = ltw[dd * 65 + lane];
                Vtbh[tbase + (size_t)(nt*16 + dd) * 2048 + si0 + lane] = f2bf(v);
            }
            __builtin_amdgcn_wave_barrier();
        }
    }
}

// ---- flash attention v7: j-split x2 (partial O + partial l), padded LDS,
//      register-resident P via S^T trick, 4 waves x 32 Q-rows ----
__global__ __launch_bounds__(256, 4) void k_attn(
    const u16* __restrict__ Qbh, const u16* __restrict__ Vbh,
    const u16* __restrict__ Vtbh,
    u16* __restrict__ part0, u16* __restrict__ part1, float* __restrict__ lsum)
{
    __shared__ __align__(16) u16 Vs[2][64 * 68];    // V[j][d], stride 68
    __shared__ __align__(16) u16 Vts[2][64 * 68];   // Vt[d][j], stride 68
    const int w = threadIdx.x >> 6, lane = threadIdx.x & 63;
    const int g = lane >> 4, cq = lane & 15;
    const int bh = blockIdx.y, z = blockIdx.z;
    const int i0 = blockIdx.x * 128 + w * 32;
    const int j0 = z * 1024;

    bf16x8 aq[2][2];
    #pragma unroll
    for (int mt = 0; mt < 2; mt++)
        #pragma unroll
        for (int kk = 0; kk < 2; kk++)
            aq[mt][kk] = *(const bf16x8*)(Qbh + ((size_t)bh*2048 + i0 + mt*16 + cq)*64 + kk*32 + g*8);

    // staging: lane covers row sr, 16 cols at sc (two bf16x8)
    const int sr = w * 16 + (lane >> 2), sc = (lane & 3) * 16;
    const u16* gvs = Vbh  + ((size_t)bh*2048 + j0 + sr) * 64 + sc;
    const u16* gvt = Vtbh + ((size_t)bh*64 + sr) * 2048 + j0 + sc;
    const int ls = sr * 68 + sc;

    {   // prologue: stage tile 0
        bf16x8 a0 = *(const bf16x8*)gvs,       a1 = *(const bf16x8*)(gvs + 8);
        bf16x8 b0 = *(const bf16x8*)gvt,       b1 = *(const bf16x8*)(gvt + 8);
        *(bf16x8*)&Vs[0][ls]  = a0;  *(bf16x8*)&Vs[0][ls + 8]  = a1;
        *(bf16x8*)&Vts[0][ls] = b0;  *(bf16x8*)&Vts[0][ls + 8] = b1;
    }

    const f32x4 zero = {0.f, 0.f, 0.f, 0.f};
    f32x4 o[2][4]; float fl[2] = {0.f, 0.f};
    #pragma unroll
    for (int mt = 0; mt < 2; mt++)
        #pragma unroll
        for (int t = 0; t < 4; t++) o[mt][t] = zero;

    for (int jt = 0; jt < 16; jt++){
        const int buf = jt & 1;
        __syncthreads();   // staged buf ready; buf^1's old readers done
        bf16x8 na0, na1, nb0, nb1;
        if (jt < 15){
            na0 = *(const bf16x8*)(gvs + (size_t)(jt + 1) * 4096);
            na1 = *(const bf16x8*)(gvs + (size_t)(jt + 1) * 4096 + 8);
            nb0 = *(const bf16x8*)(gvt + (size_t)(jt + 1) * 64);
            nb1 = *(const bf16x8*)(gvt + (size_t)(jt + 1) * 64 + 8);
        }
        // QK^T (S^T in C-layout) + exp2 + pack -> PV B-operands, all registers
        bf16x4 pk[2][4];
        #pragma unroll
        for (int t = 0; t < 4; t++){
            bf16x8 bv0 = *(const bf16x8*)&Vs[buf][(t*16 + cq)*68 + g*8];
            bf16x8 bv1 = *(const bf16x8*)&Vs[buf][(t*16 + cq)*68 + 32 + g*8];
            #pragma unroll
            for (int mt = 0; mt < 2; mt++){
                f32x4 s = __builtin_amdgcn_mfma_f32_16x16x32_bf16(bv0, aq[mt][0], zero, 0, 0, 0);
                s = __builtin_amdgcn_mfma_f32_16x16x32_bf16(bv1, aq[mt][1], s, 0, 0, 0);
                #pragma unroll
                for (int r = 0; r < 4; r++) s[r] = __builtin_amdgcn_exp2f(s[r]);
                fl[mt] += (s[0] + s[1]) + (s[2] + s[3]);
                union { bf16x4 v; uint32_t wd[2]; } u;
                u.wd[0] = (fbits(s[0]) >> 16) | (fbits(s[1]) & 0xffff0000u);
                u.wd[1] = (fbits(s[2]) >> 16) | (fbits(s[3]) & 0xffff0000u);
                pk[mt][t] = u.v;
            }
        }
        // PV: O^T += Vt-frag x P^T-frag (16x16x16)
        #pragma unroll
        for (int t = 0; t < 4; t++)
            #pragma unroll
            for (int tn = 0; tn < 4; tn++){
                bf16x4 bt = *(const bf16x4*)&Vts[buf][(tn*16 + cq)*68 + t*16 + g*4];
                o[0][tn] = mfma16(bt, pk[0][t], o[0][tn]);
                o[1][tn] = mfma16(bt, pk[1][t], o[1][tn]);
            }
        if (jt < 15){
            *(bf16x8*)&Vs[buf^1][ls]  = na0;  *(bf16x8*)&Vs[buf^1][ls + 8]  = na1;
            *(bf16x8*)&Vts[buf^1][ls] = nb0;  *(bf16x8*)&Vts[buf^1][ls + 8] = nb1;
        }
    }
    // epilogue: write UNNORMALIZED partial O + partial row-sums
    const int b_idx = bh >> 3, h = bh & 7;
    u16* part = z ? part1 : part0;
    #pragma unroll
    for (int mt = 0; mt < 2; mt++){
        float sum = fl[mt];
        sum += __shfl_xor(sum, 16);
        sum += __shfl_xor(sum, 32);
        int row = b_idx*2048 + i0 + mt*16 + cq;
        if (lane < 16)
            lsum[(size_t)z*65536 + (size_t)h*8192 + row] = sum;
        #pragma unroll
        for (int tn = 0; tn < 4; tn++){
            f32x4 ov = o[mt][tn];
            uint2 pw;
            pw.x = (uint32_t)f2bf(ov[0]) | ((uint32_t)f2bf(ov[1]) << 16);
            pw.y = (uint32_t)f2bf(ov[2]) | ((uint32_t)f2bf(ov[3]) << 16);
            int col = h*64 + tn*16 + g*4;
            *(uint2*)&part[(size_t)row * 512 + col] = pw;
        }
    }
}

// ---- output GEMM: combines partials in A-staging; padded LDS, VGPR staging ----
__global__ __launch_bounds__(256) void k_gemm_out(
    const u16* __restrict__ part0, const u16* __restrict__ part1,
    const float* __restrict__ lsum,
    const u16* __restrict__ Wot, const float* __restrict__ bias_ws,
    const void* __restrict__ x_in, void* __restrict__ out)
{
    __shared__ __align__(16) u16 Als[2][128 * 68];
    __shared__ __align__(16) u16 Bls[2][64 * 68];
    const int w = threadIdx.x >> 6, lane = threadIdx.x & 63;
    const int g = lane >> 4, cq = lane & 15;
    const int wm = w & 1, wn = w >> 1;
    const int m0b = blockIdx.x * 128, n0b = blockIdx.y * 64;
    const int m0 = m0b + wm * 64, n0 = n0b + wn * 32;
    const int f = detect_f32(x_in);

    int sra[4], sca[4], srb[2], scb[2];
    #pragma unroll
    for (int i = 0; i < 4; i++){
        int flat = (w * 4 + i) * 64 + lane;
        sra[i] = flat >> 3; sca[i] = (flat & 7) * 8;
    }
    #pragma unroll
    for (int i = 0; i < 2; i++){
        int flat = (w * 2 + i) * 64 + lane;
        srb[i] = flat >> 3; scb[i] = (flat & 7) * 8;
    }

    const f32x4 zero = {0.f, 0.f, 0.f, 0.f};
    f32x4 acc[4][2];
    #pragma unroll
    for (int i = 0; i < 4; i++)
        #pragma unroll
        for (int j = 0; j < 2; j++) acc[i][j] = zero;

    bf16x8 pa0[4], pa1[4], pb[2]; float pr[4];
    // load kt=0
    #pragma unroll
    for (int i = 0; i < 4; i++){
        int row = m0b + sra[i];
        pa0[i] = *(const bf16x8*)&part0[(size_t)row * 512 + sca[i]];
        pa1[i] = *(const bf16x8*)&part1[(size_t)row * 512 + sca[i]];
        pr[i] = 1.f / (lsum[row] + lsum[65536 + row]);   // h=0
    }
    #pragma unroll
    for (int i = 0; i < 2; i++)
        pb[i] = *(const bf16x8*)&Wot[(size_t)(n0b + srb[i]) * 512 + scb[i]];
    // combine+write kt=0 into buf0
    #pragma unroll
    for (int i = 0; i < 4; i++){
        union { bf16x8 v; u16 e[8]; } a8;
        #pragma unroll
        for (int e = 0; e < 8; e++)
            a8.e[e] = f2bf((bf2f((u16)pa0[i][e]) + bf2f((u16)pa1[i][e])) * pr[i]);
        *(bf16x8*)&Als[0][sra[i]*68 + sca[i]] = a8.v;
    }
    #pragma unroll
    for (int i = 0; i < 2; i++)
        *(bf16x8*)&Bls[0][srb[i]*68 + scb[i]] = pb[i];

    for (int kt = 0; kt < 8; kt++){
        const int buf = kt & 1;
        __syncthreads();
        if (kt < 7){
            const int kk = (kt + 1) * 64, h = kt + 1;
            #pragma unroll
            for (int i = 0; i < 4; i++){
                int row = m0b + sra[i];
                pa0[i] = *(const bf16x8*)&part0[(size_t)row * 512 + kk + sca[i]];
                pa1[i] = *(const bf16x8*)&part1[(size_t)row * 512 + kk + sca[i]];
                pr[i] = 1.f / (lsum[(size_t)h*8192 + row] + lsum[65536 + (size_t)h*8192 + row]);
            }
            #pragma unroll
            for (int i = 0; i < 2; i++)
                pb[i] = *(const bf16x8*)&Wot[(size_t)(n0b + srb[i]) * 512 + kk + scb[i]];
        }
        #pragma unroll
        for (int ks = 0; ks < 2; ks++){
            bf16x8 a[4], b[2];
            #pragma unroll
            for (int mt = 0; mt < 4; mt++)
                a[mt] = *(const bf16x8*)&Als[buf][(wm*64 + mt*16 + cq)*68 + ks*32 + g*8];
            #pragma unroll
            for (int nt = 0; nt < 2; nt++)
                b[nt] = *(const bf16x8*)&Bls[buf][(wn*32 + nt*16 + cq)*68 + ks*32 + g*8];
            #pragma unroll
            for (int mt = 0; mt < 4; mt++)
                #pragma unroll
                for (int nt = 0; nt < 2; nt++)
                    acc[mt][nt] = __builtin_amdgcn_mfma_f32_16x16x32_bf16(a[mt], b[nt], acc[mt][nt], 0, 0, 0);
        }
        if (kt < 7){
            #pragma unroll
            for (int i = 0; i < 4; i++){
                union { bf16x8 v; u16 e[8]; } a8;
                #pragma unroll
                for (int e = 0; e < 8; e++)
                    a8.e[e] = f2bf((bf2f((u16)pa0[i][e]) + bf2f((u16)pa1[i][e])) * pr[i]);
                *(bf16x8*)&Als[buf^1][sra[i]*68 + sca[i]] = a8.v;
            }
            #pragma unroll
            for (int i = 0; i < 2; i++)
                *(bf16x8*)&Bls[buf^1][srb[i]*68 + scb[i]] = pb[i];
        }
    }
    #pragma unroll
    for (int mt = 0; mt < 4; mt++)
        #pragma unroll
        for (int nt = 0; nt < 2; nt++)
            #pragma unroll
            for (int r = 0; r < 4; r++){
                int row = m0 + mt*16 + g*4 + r;
                int col = n0 + nt*16 + cq;
                size_t idx = (size_t)row * 512 + col;
                float resid = f ? ((const float*)x_in)[idx] : bf2f(((const u16*)x_in)[idx]);
                float v = acc[mt][nt][r] + bias_ws[1024 + col] + resid;
                if (f) ((float*)out)[idx] = v;
                else   ((u16*)out)[idx] = f2bf(v);
            }
}

extern "C" void kernel_launch(void* const* d_in, const int* in_sizes, int n_in,
                              void* d_out, int out_size, void* d_ws, size_t ws_size,
                              hipStream_t stream){
    const void* x_in = d_in[0];
    const void* c_in = d_in[1];
    const void* Wq = d_in[2]; const void* bq = d_in[3];
    const void* Wv = d_in[6]; const void* bv = d_in[7];
    const void* Wo = d_in[8]; const void* bo = d_in[9];

    if (ws_size < WS_NEEDED){
        hipMemsetAsync(d_out, 0, (size_t)out_size * 2, stream);
        return;
    }
    char* ws = (char*)d_ws;
    u16* c_bf  = (u16*)(ws + OFF_CBF);
    u16* x_bf  = (u16*)(ws + OFF_XBF);
    u16* Qbh   = (u16*)(ws + OFF_QBH);
    u16* Vbh   = (u16*)(ws + OFF_VBH);
    u16* Vtbh  = (u16*)(ws + OFF_VTBH);
    u16* part0 = (u16*)(ws + OFF_ATTN);
    u16* part1 = (u16*)(ws + OFF_CBF);    // c_bf region, free after gemm_qv
    float* lsum = (float*)(ws + OFF_XBF); // x_bf region, free after gemm_qv
    u16* Wqt   = (u16*)(ws + OFF_WQT);
    u16* Wvt   = (u16*)(ws + OFF_WVT);
    u16* Wot   = (u16*)(ws + OFF_WOT);
    float* bias_ws = (float*)(ws + OFF_BIAS);
    float* cos_t   = (float*)(ws + OFF_COS);
    float* sin_t   = (float*)(ws + OFF_SIN);

    k_prep<<<11520, 256, 0, stream>>>(c_in, x_in, Wq, Wv, Wo, bq, bv, bo,
                                      c_bf, x_bf, Wqt, Wvt, Wot, bias_ws, cos_t, sin_t);
    k_gemm_qv<<<dim3(64, 4, 2), 256, 0, stream>>>(c_bf, x_bf, Wqt, Wvt, bias_ws,
                                                  cos_t, sin_t, Qbh, Vbh, Vtbh);
    k_attn<<<dim3(16, 32, 2), 256, 0, stream>>>(Qbh, Vbh, Vtbh, part0, part1, lsum);
    k_gemm_out<<<dim3(64, 8), 256, 0, stream>>>(part0, part1, lsum, Wot, bias_ws,
                                                x_in, d_out);
}